// Round 3
// baseline (3299.757 us; speedup 1.0000x reference)
//
#include <hip/hip_runtime.h>

#define B_ 64
#define T_ 512
#define D_ 512
#define H_ 512
#define NG 2048  // 4H

typedef __attribute__((ext_vector_type(8))) short short8;
typedef __attribute__((ext_vector_type(4))) float floatx4;

static __device__ __forceinline__ unsigned short f2bf(float f) {
    unsigned int u = __float_as_uint(f);
    return (unsigned short)((u + 0x7FFFu + ((u >> 16) & 1u)) >> 16);  // RNE
}

static __device__ __forceinline__ short8 pack8(float4 a, float4 b) {
    short8 r;
    r[0] = (short)f2bf(a.x); r[1] = (short)f2bf(a.y);
    r[2] = (short)f2bf(a.z); r[3] = (short)f2bf(a.w);
    r[4] = (short)f2bf(b.x); r[5] = (short)f2bf(b.y);
    r[6] = (short)f2bf(b.z); r[7] = (short)f2bf(b.w);
    return r;
}

static __device__ __forceinline__ float sigm(float x) { return 1.0f / (1.0f + __expf(-x)); }
static __device__ __forceinline__ float tanh_(float x) {
    float e = __expf(2.0f * x);
    return 1.0f - 2.0f / (e + 1.0f);
}

// ---- transpose Wi/Wh ([512][2048] f32) -> bf16 [2048][512], LDS-tiled ----
__global__ __launch_bounds__(256) void transpose_w(
    const float* __restrict__ Wi, const float* __restrict__ Wh,
    unsigned short* __restrict__ WiT, unsigned short* __restrict__ WhT)
{
    __shared__ float tile[64][65];
    const float* src = blockIdx.z ? Wh : Wi;
    unsigned short* dst = blockIdx.z ? WhT : WiT;
    const int n0 = blockIdx.x * 64, k0 = blockIdx.y * 64;
    const int cx = threadIdx.x & 63, ry = threadIdx.x >> 6;
#pragma unroll
    for (int i = 0; i < 16; ++i) {
        int k = ry * 16 + i;
        tile[k][cx] = src[(size_t)(k0 + k) * NG + n0 + cx];
    }
    __syncthreads();
#pragma unroll
    for (int i = 0; i < 16; ++i) {
        int n = ry * 16 + i;
        dst[(size_t)(n0 + n) * D_ + k0 + cx] = f2bf(tile[cx][n]);
    }
}

// ---- zx[b][t][4H] (fp16) = flip(x) @ Wi + b ; 128x128 tile, 4 waves ----
__global__ __launch_bounds__(256) void zx_gemm(
    const float* __restrict__ x, const int* __restrict__ lengths,
    const unsigned short* __restrict__ WiT, const float* __restrict__ bias,
    const int* __restrict__ revp, _Float16* __restrict__ zx)
{
    __shared__ unsigned short a_lds[128][40];
    __shared__ unsigned short b_lds[128][40];

    const int mt = blockIdx.x, nt = blockIdx.y;
    const int tid = threadIdx.x;
    const int lane = tid & 63, w = tid >> 6;
    const int wm = w & 1, wn = w >> 1;

    const int b = mt >> 2;
    const int len = lengths[b];
    const int rev = revp[0];

    const int r = tid >> 1;
    const int kh = (tid & 1) << 4;
    const int t = ((mt & 3) << 7) + r;
    const int src_t = rev ? ((T_ - 1 - t + len) & (T_ - 1)) : t;
    const float* arow = x + ((size_t)b * T_ + src_t) * D_;
    const unsigned short* brow = WiT + (size_t)(nt * 128 + r) * D_;

    floatx4 acc[4][4];
#pragma unroll
    for (int i = 0; i < 4; ++i)
#pragma unroll
        for (int j = 0; j < 4; ++j) acc[i][j] = (floatx4){0.f, 0.f, 0.f, 0.f};

    for (int kt = 0; kt < D_ / 32; ++kt) {
        const float4* ap = (const float4*)(arow + kt * 32 + kh);
        float4 a0 = ap[0], a1 = ap[1], a2 = ap[2], a3 = ap[3];
        const uint4* bp = (const uint4*)(brow + kt * 32 + kh);
        uint4 bq0 = bp[0], bq1 = bp[1];
        *(short8*)&a_lds[r][kh]     = pack8(a0, a1);
        *(short8*)&a_lds[r][kh + 8] = pack8(a2, a3);
        *(uint4*)&b_lds[r][kh]     = bq0;
        *(uint4*)&b_lds[r][kh + 8] = bq1;
        __syncthreads();

        short8 af[4], bfr[4];
#pragma unroll
        for (int mi = 0; mi < 4; ++mi)
            af[mi] = *(const short8*)&a_lds[wm * 64 + mi * 16 + (lane & 15)][(lane >> 4) << 3];
#pragma unroll
        for (int ni = 0; ni < 4; ++ni)
            bfr[ni] = *(const short8*)&b_lds[wn * 64 + ni * 16 + (lane & 15)][(lane >> 4) << 3];
#pragma unroll
        for (int mi = 0; mi < 4; ++mi)
#pragma unroll
            for (int ni = 0; ni < 4; ++ni)
                acc[mi][ni] = __builtin_amdgcn_mfma_f32_16x16x32_bf16(af[mi], bfr[ni], acc[mi][ni], 0, 0, 0);
        __syncthreads();
    }

#pragma unroll
    for (int mi = 0; mi < 4; ++mi) {
#pragma unroll
        for (int ni = 0; ni < 4; ++ni) {
            int row = wm * 64 + mi * 16 + ((lane >> 4) << 2);
            int col = nt * 128 + wn * 64 + ni * 16 + (lane & 15);
            float bv = bias[col];
            size_t base = (size_t)(mt * 128 + row) * NG + col;
#pragma unroll
            for (int v = 0; v < 4; ++v)
                zx[base + (size_t)v * NG] = (_Float16)(acc[mi][ni][v] + bv);
        }
    }
}

// ---- persistent LSTM recurrence ----
// 64 blocks = 4 batch-groups(16 batches) x 16 h-blocks(32 units = 128 gate cols).
// 4 waves/block, N-split: wave w owns 32 cols = 4 gates x 8 units, full K=512 in regs.
// Exchange: tagged dwords (bf16 | step<<16), relaxed agent atomics; poll = the load.
__global__ __launch_bounds__(256, 1) void lstm_rec(
    const _Float16* __restrict__ zx, const unsigned short* __restrict__ WhT,
    const float* __restrict__ c0, const float* __restrict__ h0,
    const int* __restrict__ lengths, const int* __restrict__ revp,
    float* __restrict__ out, unsigned int* __restrict__ h_pub)
{
    __shared__ unsigned short h_lds[16][520];   // 16 batches x 512 units (+pad)

    const int bid = blockIdx.x;
    const int gb = bid & 3, gh = bid >> 2;
    const int tid = threadIdx.x;
    const int lane = tid & 63, w = tid >> 6;
    const int b0 = gb * 16, u0 = gh * 32;
    const int rev = revp[0];

    const int colh = lane & 15;
    const int rr = (lane >> 4) << 2;   // D-row base = batch base
    const int cg = colh >> 3;          // gate-pair selector (0:{i,g} 1:{f,o})
    const int cu = colh & 7;
    const int uu = w * 8 + cu;         // unit within block
    const int khw = (lane >> 4) << 3;  // k-offset within 32-chunk

    int len_v[4]; float c[4];
#pragma unroll
    for (int v = 0; v < 4; ++v) {
        len_v[v] = lengths[b0 + rr + v];
        c[v] = c0[(size_t)(b0 + rr + v) * H_ + u0 + uu];
    }

    // Wh fragments: bw[kk][ni] for gate = ni*2+cg, unit = u0+uu, k = kk*32+khw+0..7
    short8 bw[16][2];
#pragma unroll
    for (int ni = 0; ni < 2; ++ni) {
        const unsigned short* src = WhT + (size_t)((ni * 2 + cg) * H_ + u0 + uu) * D_ + khw;
#pragma unroll
        for (int kk = 0; kk < 16; ++kk)
            bw[kk][ni] = *(const short8*)(src + kk * 32);
    }

    float zxv[2][4];
#pragma unroll
    for (int ni = 0; ni < 2; ++ni)
#pragma unroll
        for (int v = 0; v < 4; ++v)
            zxv[ni][v] = (float)zx[((size_t)(b0 + rr + v) * T_) * NG + (ni * 2 + cg) * H_ + u0 + uu];

    // staging map: thread -> row r (batch), 32-col chunk
    const int sr = tid >> 4;
    const int scc = (tid & 15) << 5;

    for (int s = 0; s < T_; ++s) {
        // ---- stage h(s)[16][512] -> LDS ----
        if (s == 0) {
            const float* hp = h0 + (size_t)(b0 + sr) * H_ + scc;
#pragma unroll
            for (int q = 0; q < 4; ++q) {
                float4 f0 = *(const float4*)(hp + q * 8);
                float4 f1 = *(const float4*)(hp + q * 8 + 4);
                *(short8*)&h_lds[sr][scc + q * 8] = pack8(f0, f1);
            }
        } else {
            const unsigned int* src = h_pub + ((size_t)(s & 1) * B_ + b0 + sr) * H_ + scc;
#pragma unroll
            for (int half = 0; half < 2; ++half) {
                const unsigned int* sp = src + half * 16;
                unsigned int dwv[16];
                for (;;) {
                    bool ok = true;
#pragma unroll
                    for (int j = 0; j < 16; ++j)
                        dwv[j] = __hip_atomic_load(sp + j, __ATOMIC_RELAXED, __HIP_MEMORY_SCOPE_AGENT);
#pragma unroll
                    for (int j = 0; j < 16; ++j)
                        ok &= ((dwv[j] >> 16) == (unsigned)s);
                    if (ok) break;
                    __builtin_amdgcn_s_sleep(1);
                }
                short8 p0, p1;
#pragma unroll
                for (int j = 0; j < 8; ++j) {
                    p0[j] = (short)(dwv[j] & 0xffffu);
                    p1[j] = (short)(dwv[j + 8] & 0xffffu);
                }
                *(short8*)&h_lds[sr][scc + half * 16]     = p0;
                *(short8*)&h_lds[sr][scc + half * 16 + 8] = p1;
            }
        }
        __syncthreads();

        // ---- z = h @ Wh (full K per wave, 32 MFMA) ----
        floatx4 acc[2];
        acc[0] = (floatx4){0.f, 0.f, 0.f, 0.f};
        acc[1] = (floatx4){0.f, 0.f, 0.f, 0.f};
#pragma unroll
        for (int kk = 0; kk < 16; ++kk) {
            short8 af = *(const short8*)&h_lds[lane & 15][kk * 32 + khw];
            acc[0] = __builtin_amdgcn_mfma_f32_16x16x32_bf16(af, bw[kk][0], acc[0], 0, 0, 0);
            acc[1] = __builtin_amdgcn_mfma_f32_16x16x32_bf16(af, bw[kk][1], acc[1], 0, 0, 0);
        }

        // ---- gates: lane holds z for gates {cg, 2+cg}; shfl_xor(8) brings the other pair ----
#pragma unroll
        for (int v = 0; v < 4; ++v) {
            float own0 = acc[0][v] + zxv[0][v];        // gate cg
            float own1 = acc[1][v] + zxv[1][v];        // gate 2+cg
            float oth0 = __shfl_xor(own0, 8);          // gate 1-cg (partner)
            float oth1 = __shfl_xor(own1, 8);          // gate 3-cg
            float zi = cg ? oth0 : own0;
            float zf = cg ? own0 : oth0;
            float zg = cg ? oth1 : own1;
            float zo = cg ? own1 : oth1;
            float ig = sigm(zi), fg = sigm(zf);
            float gg = tanh_(zg), og = sigm(zo);
            float cn = fg * c[v] + ig * gg;
            float hn = og * tanh_(cn);
            c[v] = cn;

            const int b = b0 + rr + v;
            const int ug = u0 + uu;
            int orig_t = rev ? ((T_ - 1 - s + len_v[v]) & (T_ - 1)) : s;
            if (cg == 0)
                out[((size_t)b * T_ + orig_t) * H_ + ug] = hn;
            else if (s + 1 < T_) {
                unsigned int val = (unsigned int)f2bf(hn) | ((unsigned int)(s + 1) << 16);
                __hip_atomic_store(h_pub + ((size_t)((s + 1) & 1) * B_ + b) * H_ + ug, val,
                                   __ATOMIC_RELAXED, __HIP_MEMORY_SCOPE_AGENT);
            }
            if (s == len_v[v] - 1) {
                size_t fin = (size_t)B_ * T_ * H_;
                if (cg == 0) out[fin + (size_t)b * H_ + ug] = cn;
                else         out[fin + (size_t)B_ * H_ + (size_t)b * H_ + ug] = hn;
            }
        }

        // ---- zx prefetch for s+1 ----
        if (s + 1 < T_) {
#pragma unroll
            for (int ni = 0; ni < 2; ++ni)
#pragma unroll
                for (int v = 0; v < 4; ++v)
                    zxv[ni][v] = (float)zx[((size_t)(b0 + rr + v) * T_ + s + 1) * NG +
                                           (ni * 2 + cg) * H_ + u0 + uu];
        }
        __syncthreads();   // MFMA reads done before next stage overwrites h_lds
    }
}

extern "C" void kernel_launch(void* const* d_in, const int* in_sizes, int n_in,
                              void* d_out, int out_size, void* d_ws, size_t ws_size,
                              hipStream_t stream)
{
    const float* x       = (const float*)d_in[0];
    const int*   lengths = (const int*)d_in[1];
    const float* c0      = (const float*)d_in[2];
    const float* h0      = (const float*)d_in[3];
    const float* Wi      = (const float*)d_in[4];
    const float* Wh      = (const float*)d_in[5];
    const float* bias    = (const float*)d_in[6];
    const int*   revp    = (const int*)d_in[7];
    float* out = (float*)d_out;

    char* ws = (char*)d_ws;
    const size_t OFF_WIT = 0;
    const size_t OFF_WHT = 2ull << 20;
    const size_t OFF_ZX  = 4ull << 20;
    const size_t OFF_HP  = OFF_ZX + (size_t)B_ * T_ * NG * 2;   // fp16 zx
    const size_t HP_BYTES = 2ull * B_ * H_ * 4;                 // double-buffered tagged dwords
    const size_t NEED    = OFF_HP + HP_BYTES;
    if (ws_size < NEED) return;

    unsigned short* WiT = (unsigned short*)(ws + OFF_WIT);
    unsigned short* WhT = (unsigned short*)(ws + OFF_WHT);
    _Float16* zx        = (_Float16*)(ws + OFF_ZX);
    unsigned int* h_pub = (unsigned int*)(ws + OFF_HP);

    hipMemsetAsync(h_pub, 0, HP_BYTES, stream);   // invalidate tags each call
    dim3 gt(32, 8, 2);
    transpose_w<<<gt, 256, 0, stream>>>(Wi, Wh, WiT, WhT);
    dim3 g1(256, 16);
    zx_gemm<<<g1, 256, 0, stream>>>(x, lengths, WiT, bias, revp, zx);
    lstm_rec<<<64, 256, 0, stream>>>(zx, WhT, c0, h0, lengths, revp, out, h_pub);
}

// Round 4
// 2459.793 us; speedup vs baseline: 1.3415x; 1.3415x over previous
//
#include <hip/hip_runtime.h>

#define B_ 64
#define T_ 512
#define D_ 512
#define H_ 512
#define NG 2048  // 4H

typedef __attribute__((ext_vector_type(8))) short short8;
typedef __attribute__((ext_vector_type(4))) float floatx4;
typedef __attribute__((ext_vector_type(4))) unsigned int uintx4;

static __device__ __forceinline__ unsigned short f2bf(float f) {
    unsigned int u = __float_as_uint(f);
    return (unsigned short)((u + 0x7FFFu + ((u >> 16) & 1u)) >> 16);  // RNE
}

static __device__ __forceinline__ short8 pack8(float4 a, float4 b) {
    short8 r;
    r[0] = (short)f2bf(a.x); r[1] = (short)f2bf(a.y);
    r[2] = (short)f2bf(a.z); r[3] = (short)f2bf(a.w);
    r[4] = (short)f2bf(b.x); r[5] = (short)f2bf(b.y);
    r[6] = (short)f2bf(b.z); r[7] = (short)f2bf(b.w);
    return r;
}

static __device__ __forceinline__ float sigm(float x) { return 1.0f / (1.0f + __expf(-x)); }
static __device__ __forceinline__ float tanh_(float x) {
    float e = __expf(2.0f * x);
    return 1.0f - 2.0f / (e + 1.0f);
}

// ---- transpose Wi/Wh ([512][2048] f32) -> bf16 [2048][512], LDS-tiled ----
__global__ __launch_bounds__(256) void transpose_w(
    const float* __restrict__ Wi, const float* __restrict__ Wh,
    unsigned short* __restrict__ WiT, unsigned short* __restrict__ WhT)
{
    __shared__ float tile[64][65];
    const float* src = blockIdx.z ? Wh : Wi;
    unsigned short* dst = blockIdx.z ? WhT : WiT;
    const int n0 = blockIdx.x * 64, k0 = blockIdx.y * 64;
    const int cx = threadIdx.x & 63, ry = threadIdx.x >> 6;
#pragma unroll
    for (int i = 0; i < 16; ++i) {
        int k = ry * 16 + i;
        tile[k][cx] = src[(size_t)(k0 + k) * NG + n0 + cx];
    }
    __syncthreads();
#pragma unroll
    for (int i = 0; i < 16; ++i) {
        int n = ry * 16 + i;
        dst[(size_t)(n0 + n) * D_ + k0 + cx] = f2bf(tile[cx][n]);
    }
}

// ---- zx[b][t][4H] (fp16) = flip(x) @ Wi + b ; 128x128 tile, 4 waves ----
__global__ __launch_bounds__(256) void zx_gemm(
    const float* __restrict__ x, const int* __restrict__ lengths,
    const unsigned short* __restrict__ WiT, const float* __restrict__ bias,
    const int* __restrict__ revp, _Float16* __restrict__ zx)
{
    __shared__ unsigned short a_lds[128][40];
    __shared__ unsigned short b_lds[128][40];

    const int mt = blockIdx.x, nt = blockIdx.y;
    const int tid = threadIdx.x;
    const int lane = tid & 63, w = tid >> 6;
    const int wm = w & 1, wn = w >> 1;

    const int b = mt >> 2;
    const int len = lengths[b];
    const int rev = revp[0];

    const int r = tid >> 1;
    const int kh = (tid & 1) << 4;
    const int t = ((mt & 3) << 7) + r;
    const int src_t = rev ? ((T_ - 1 - t + len) & (T_ - 1)) : t;
    const float* arow = x + ((size_t)b * T_ + src_t) * D_;
    const unsigned short* brow = WiT + (size_t)(nt * 128 + r) * D_;

    floatx4 acc[4][4];
#pragma unroll
    for (int i = 0; i < 4; ++i)
#pragma unroll
        for (int j = 0; j < 4; ++j) acc[i][j] = (floatx4){0.f, 0.f, 0.f, 0.f};

    for (int kt = 0; kt < D_ / 32; ++kt) {
        const float4* ap = (const float4*)(arow + kt * 32 + kh);
        float4 a0 = ap[0], a1 = ap[1], a2 = ap[2], a3 = ap[3];
        const uint4* bp = (const uint4*)(brow + kt * 32 + kh);
        uint4 bq0 = bp[0], bq1 = bp[1];
        *(short8*)&a_lds[r][kh]     = pack8(a0, a1);
        *(short8*)&a_lds[r][kh + 8] = pack8(a2, a3);
        *(uint4*)&b_lds[r][kh]     = bq0;
        *(uint4*)&b_lds[r][kh + 8] = bq1;
        __syncthreads();

        short8 af[4], bfr[4];
#pragma unroll
        for (int mi = 0; mi < 4; ++mi)
            af[mi] = *(const short8*)&a_lds[wm * 64 + mi * 16 + (lane & 15)][(lane >> 4) << 3];
#pragma unroll
        for (int ni = 0; ni < 4; ++ni)
            bfr[ni] = *(const short8*)&b_lds[wn * 64 + ni * 16 + (lane & 15)][(lane >> 4) << 3];
#pragma unroll
        for (int mi = 0; mi < 4; ++mi)
#pragma unroll
            for (int ni = 0; ni < 4; ++ni)
                acc[mi][ni] = __builtin_amdgcn_mfma_f32_16x16x32_bf16(af[mi], bfr[ni], acc[mi][ni], 0, 0, 0);
        __syncthreads();
    }

#pragma unroll
    for (int mi = 0; mi < 4; ++mi) {
#pragma unroll
        for (int ni = 0; ni < 4; ++ni) {
            int row = wm * 64 + mi * 16 + ((lane >> 4) << 2);
            int col = nt * 128 + wn * 64 + ni * 16 + (lane & 15);
            float bv = bias[col];
            size_t base = (size_t)(mt * 128 + row) * NG + col;
#pragma unroll
            for (int v = 0; v < 4; ++v)
                zx[base + (size_t)v * NG] = (_Float16)(acc[mi][ni][v] + bv);
        }
    }
}

// ---- persistent LSTM recurrence ----
// 64 blocks = 4 batch-groups(16 batches) x 16 h-blocks(32 units). 4 waves, N-split,
// Wh register-resident. Exchange: tagged dwords (bf16 | (s)<<16), cache-bypassing
// wide loads (global_load_dwordx4 sc0 sc1) -> 1 round-trip per step, zero fences.
__global__ __launch_bounds__(256, 1) void lstm_rec(
    const _Float16* __restrict__ zx, const unsigned short* __restrict__ WhT,
    const float* __restrict__ c0, const float* __restrict__ h0,
    const int* __restrict__ lengths, const int* __restrict__ revp,
    float* __restrict__ out, unsigned int* __restrict__ h_pub)
{
    __shared__ unsigned short h_lds[16][520];   // 16 batches x 512 units (+pad)

    const int bid = blockIdx.x;
    const int gb = bid & 3, gh = bid >> 2;
    const int tid = threadIdx.x;
    const int lane = tid & 63, w = tid >> 6;
    const int b0 = gb * 16, u0 = gh * 32;
    const int rev = revp[0];

    const int colh = lane & 15;
    const int rr = (lane >> 4) << 2;   // batch base within group (MFMA D rows)
    const int cg = colh >> 3;          // gate-pair selector (0:{i,g} 1:{f,o})
    const int cu = colh & 7;
    const int uu = w * 8 + cu;         // unit within block
    const int khw = (lane >> 4) << 3;  // k-offset within 32-chunk

    int len_v[4]; float c[4];
#pragma unroll
    for (int v = 0; v < 4; ++v) {
        len_v[v] = lengths[b0 + rr + v];
        c[v] = c0[(size_t)(b0 + rr + v) * H_ + u0 + uu];
    }

    // Wh fragments: bw[kk][ni] for gate = ni*2+cg, unit = u0+uu, k = kk*32+khw+0..7
    short8 bw[16][2];
#pragma unroll
    for (int ni = 0; ni < 2; ++ni) {
        const unsigned short* src = WhT + (size_t)((ni * 2 + cg) * H_ + u0 + uu) * D_ + khw;
#pragma unroll
        for (int kk = 0; kk < 16; ++kk)
            bw[kk][ni] = *(const short8*)(src + kk * 32);
    }

    float zxv[2][4];
#pragma unroll
    for (int ni = 0; ni < 2; ++ni)
#pragma unroll
        for (int v = 0; v < 4; ++v)
            zxv[ni][v] = (float)zx[((size_t)(b0 + rr + v) * T_) * NG + (ni * 2 + cg) * H_ + u0 + uu];

    // staging map: thread -> batch row sr, 32-unit chunk at scc
    const int sr = tid >> 4;
    const int scc = (tid & 15) << 5;

    for (int s = 0; s < T_; ++s) {
        // ---- stage h(s)[16][512] -> LDS ----
        if (s == 0) {
            const float* hp = h0 + (size_t)(b0 + sr) * H_ + scc;
#pragma unroll
            for (int q = 0; q < 4; ++q) {
                float4 f0 = *(const float4*)(hp + q * 8);
                float4 f1 = *(const float4*)(hp + q * 8 + 4);
                *(short8*)&h_lds[sr][scc + q * 8] = pack8(f0, f1);
            }
        } else {
            const unsigned int* sp = h_pub + ((size_t)(s & 1) * B_ + b0 + sr) * H_ + scc;
            const unsigned int tag = (unsigned int)s << 16;
            uintx4 d0, d1, d2, d3, d4, d5, d6, d7;
            for (;;) {
                asm volatile(
                    "global_load_dwordx4 %0, %8, off sc0 sc1\n\t"
                    "global_load_dwordx4 %1, %9, off sc0 sc1\n\t"
                    "global_load_dwordx4 %2, %10, off sc0 sc1\n\t"
                    "global_load_dwordx4 %3, %11, off sc0 sc1\n\t"
                    "global_load_dwordx4 %4, %12, off sc0 sc1\n\t"
                    "global_load_dwordx4 %5, %13, off sc0 sc1\n\t"
                    "global_load_dwordx4 %6, %14, off sc0 sc1\n\t"
                    "global_load_dwordx4 %7, %15, off sc0 sc1\n\t"
                    "s_waitcnt vmcnt(0)"
                    : "=&v"(d0), "=&v"(d1), "=&v"(d2), "=&v"(d3),
                      "=&v"(d4), "=&v"(d5), "=&v"(d6), "=&v"(d7)
                    : "v"(sp), "v"(sp + 4), "v"(sp + 8), "v"(sp + 12),
                      "v"(sp + 16), "v"(sp + 20), "v"(sp + 24), "v"(sp + 28)
                    : "memory");
                bool ok = true;
#pragma unroll
                for (int e = 0; e < 4; ++e) {
                    ok &= ((d0[e] & 0xffff0000u) == tag);
                    ok &= ((d1[e] & 0xffff0000u) == tag);
                    ok &= ((d2[e] & 0xffff0000u) == tag);
                    ok &= ((d3[e] & 0xffff0000u) == tag);
                    ok &= ((d4[e] & 0xffff0000u) == tag);
                    ok &= ((d5[e] & 0xffff0000u) == tag);
                    ok &= ((d6[e] & 0xffff0000u) == tag);
                    ok &= ((d7[e] & 0xffff0000u) == tag);
                }
                if (ok) break;
                __builtin_amdgcn_s_sleep(1);
            }
            uint4 w0, w1;
            w0.x = (d0[0] & 0xffffu) | (d0[1] << 16);
            w0.y = (d0[2] & 0xffffu) | (d0[3] << 16);
            w0.z = (d1[0] & 0xffffu) | (d1[1] << 16);
            w0.w = (d1[2] & 0xffffu) | (d1[3] << 16);
            w1.x = (d2[0] & 0xffffu) | (d2[1] << 16);
            w1.y = (d2[2] & 0xffffu) | (d2[3] << 16);
            w1.z = (d3[0] & 0xffffu) | (d3[1] << 16);
            w1.w = (d3[2] & 0xffffu) | (d3[3] << 16);
            *(uint4*)&h_lds[sr][scc]     = w0;
            *(uint4*)&h_lds[sr][scc + 8] = w1;
            w0.x = (d4[0] & 0xffffu) | (d4[1] << 16);
            w0.y = (d4[2] & 0xffffu) | (d4[3] << 16);
            w0.z = (d5[0] & 0xffffu) | (d5[1] << 16);
            w0.w = (d5[2] & 0xffffu) | (d5[3] << 16);
            w1.x = (d6[0] & 0xffffu) | (d6[1] << 16);
            w1.y = (d6[2] & 0xffffu) | (d6[3] << 16);
            w1.z = (d7[0] & 0xffffu) | (d7[1] << 16);
            w1.w = (d7[2] & 0xffffu) | (d7[3] << 16);
            *(uint4*)&h_lds[sr][scc + 16] = w0;
            *(uint4*)&h_lds[sr][scc + 24] = w1;
        }
        __syncthreads();

        // ---- z = h @ Wh (full K per wave, 32 MFMA) ----
        floatx4 acc[2];
        acc[0] = (floatx4){0.f, 0.f, 0.f, 0.f};
        acc[1] = (floatx4){0.f, 0.f, 0.f, 0.f};
#pragma unroll
        for (int kk = 0; kk < 16; ++kk) {
            short8 af = *(const short8*)&h_lds[lane & 15][kk * 32 + khw];
            acc[0] = __builtin_amdgcn_mfma_f32_16x16x32_bf16(af, bw[kk][0], acc[0], 0, 0, 0);
            acc[1] = __builtin_amdgcn_mfma_f32_16x16x32_bf16(af, bw[kk][1], acc[1], 0, 0, 0);
        }

        // ---- zx prefetch for s+1 (issue before gate math) ----
        float zxn[2][4];
        if (s + 1 < T_) {
#pragma unroll
            for (int ni = 0; ni < 2; ++ni)
#pragma unroll
                for (int v = 0; v < 4; ++v)
                    zxn[ni][v] = (float)zx[((size_t)(b0 + rr + v) * T_ + s + 1) * NG +
                                           (ni * 2 + cg) * H_ + u0 + uu];
        }

        // ---- gates; publish h first (unblocks other blocks), then out stores ----
        float hn_v[4], cn_v[4];
#pragma unroll
        for (int v = 0; v < 4; ++v) {
            float own0 = acc[0][v] + zxv[0][v];        // gate cg
            float own1 = acc[1][v] + zxv[1][v];        // gate 2+cg
            float oth0 = __shfl_xor(own0, 8);          // gate 1-cg
            float oth1 = __shfl_xor(own1, 8);          // gate 3-cg
            float zi = cg ? oth0 : own0;
            float zf = cg ? own0 : oth0;
            float zg = cg ? oth1 : own1;
            float zo = cg ? own1 : oth1;
            float ig = sigm(zi), fg = sigm(zf);
            float gg = tanh_(zg), og = sigm(zo);
            float cn = fg * c[v] + ig * gg;
            float hn = og * tanh_(cn);
            c[v] = cn; cn_v[v] = cn; hn_v[v] = hn;
            if (cg == 1 && s + 1 < T_) {
                unsigned int val = (unsigned int)f2bf(hn) | ((unsigned int)(s + 1) << 16);
                unsigned int* dst = h_pub + ((size_t)((s + 1) & 1) * B_ + b0 + rr + v) * H_ + u0 + uu;
                asm volatile("global_store_dword %0, %1, off sc0 sc1"
                             :: "v"(dst), "v"(val) : "memory");
            }
        }
#pragma unroll
        for (int v = 0; v < 4; ++v) {
            const int b = b0 + rr + v;
            const int ug = u0 + uu;
            int orig_t = rev ? ((T_ - 1 - s + len_v[v]) & (T_ - 1)) : s;
            if (cg == 0)
                out[((size_t)b * T_ + orig_t) * H_ + ug] = hn_v[v];
            if (s == len_v[v] - 1) {
                size_t fin = (size_t)B_ * T_ * H_;
                if (cg == 0) out[fin + (size_t)b * H_ + ug] = cn_v[v];
                else         out[fin + (size_t)B_ * H_ + (size_t)b * H_ + ug] = hn_v[v];
            }
        }
#pragma unroll
        for (int ni = 0; ni < 2; ++ni)
#pragma unroll
            for (int v = 0; v < 4; ++v) zxv[ni][v] = zxn[ni][v];

        __syncthreads();   // MFMA reads done before next stage overwrites h_lds
    }
}

extern "C" void kernel_launch(void* const* d_in, const int* in_sizes, int n_in,
                              void* d_out, int out_size, void* d_ws, size_t ws_size,
                              hipStream_t stream)
{
    const float* x       = (const float*)d_in[0];
    const int*   lengths = (const int*)d_in[1];
    const float* c0      = (const float*)d_in[2];
    const float* h0      = (const float*)d_in[3];
    const float* Wi      = (const float*)d_in[4];
    const float* Wh      = (const float*)d_in[5];
    const float* bias    = (const float*)d_in[6];
    const int*   revp    = (const int*)d_in[7];
    float* out = (float*)d_out;

    char* ws = (char*)d_ws;
    const size_t OFF_WIT = 0;
    const size_t OFF_WHT = 2ull << 20;
    const size_t OFF_ZX  = 4ull << 20;
    const size_t OFF_HP  = OFF_ZX + (size_t)B_ * T_ * NG * 2;   // fp16 zx
    const size_t HP_BYTES = 2ull * B_ * H_ * 4;                 // double-buffered tagged dwords
    const size_t NEED    = OFF_HP + HP_BYTES;
    if (ws_size < NEED) return;

    unsigned short* WiT = (unsigned short*)(ws + OFF_WIT);
    unsigned short* WhT = (unsigned short*)(ws + OFF_WHT);
    _Float16* zx        = (_Float16*)(ws + OFF_ZX);
    unsigned int* h_pub = (unsigned int*)(ws + OFF_HP);

    hipMemsetAsync(h_pub, 0, HP_BYTES, stream);   // invalidate tags each call
    dim3 gt(32, 8, 2);
    transpose_w<<<gt, 256, 0, stream>>>(Wi, Wh, WiT, WhT);
    dim3 g1(256, 16);
    zx_gemm<<<g1, 256, 0, stream>>>(x, lengths, WiT, bias, revp, zx);
    lstm_rec<<<64, 256, 0, stream>>>(zx, WhT, c0, h0, lengths, revp, out, h_pub);
}

// Round 5
// 1783.623 us; speedup vs baseline: 1.8500x; 1.3791x over previous
//
#include <hip/hip_runtime.h>

#define B_ 64
#define T_ 512
#define D_ 512
#define H_ 512
#define NG 2048  // 4H

typedef __attribute__((ext_vector_type(8))) short short8;
typedef __attribute__((ext_vector_type(4))) float floatx4;
typedef __attribute__((ext_vector_type(4))) unsigned int uintx4;

static __device__ __forceinline__ unsigned short f2bf(float f) {
    unsigned int u = __float_as_uint(f);
    return (unsigned short)((u + 0x7FFFu + ((u >> 16) & 1u)) >> 16);  // RNE
}

static __device__ __forceinline__ short8 pack8(float4 a, float4 b) {
    short8 r;
    r[0] = (short)f2bf(a.x); r[1] = (short)f2bf(a.y);
    r[2] = (short)f2bf(a.z); r[3] = (short)f2bf(a.w);
    r[4] = (short)f2bf(b.x); r[5] = (short)f2bf(b.y);
    r[6] = (short)f2bf(b.z); r[7] = (short)f2bf(b.w);
    return r;
}

static __device__ __forceinline__ float sigm(float x) { return 1.0f / (1.0f + __expf(-x)); }
static __device__ __forceinline__ float tanh_(float x) {
    float e = __expf(2.0f * x);
    return 1.0f - 2.0f / (e + 1.0f);
}

// ---- transpose Wi/Wh ([512][2048] f32) -> bf16 [2048][512], LDS-tiled ----
__global__ __launch_bounds__(256) void transpose_w(
    const float* __restrict__ Wi, const float* __restrict__ Wh,
    unsigned short* __restrict__ WiT, unsigned short* __restrict__ WhT)
{
    __shared__ float tile[64][65];
    const float* src = blockIdx.z ? Wh : Wi;
    unsigned short* dst = blockIdx.z ? WhT : WiT;
    const int n0 = blockIdx.x * 64, k0 = blockIdx.y * 64;
    const int cx = threadIdx.x & 63, ry = threadIdx.x >> 6;
#pragma unroll
    for (int i = 0; i < 16; ++i) {
        int k = ry * 16 + i;
        tile[k][cx] = src[(size_t)(k0 + k) * NG + n0 + cx];
    }
    __syncthreads();
#pragma unroll
    for (int i = 0; i < 16; ++i) {
        int n = ry * 16 + i;
        dst[(size_t)(n0 + n) * D_ + k0 + cx] = f2bf(tile[cx][n]);
    }
}

// ---- zx[b][t][4H] (fp16) = flip(x) @ Wi + b ; 128x128 tile, 4 waves ----
__global__ __launch_bounds__(256) void zx_gemm(
    const float* __restrict__ x, const int* __restrict__ lengths,
    const unsigned short* __restrict__ WiT, const float* __restrict__ bias,
    const int* __restrict__ revp, _Float16* __restrict__ zx)
{
    __shared__ unsigned short a_lds[128][40];
    __shared__ unsigned short b_lds[128][40];

    const int mt = blockIdx.x, nt = blockIdx.y;
    const int tid = threadIdx.x;
    const int lane = tid & 63, w = tid >> 6;
    const int wm = w & 1, wn = w >> 1;

    const int b = mt >> 2;
    const int len = lengths[b];
    const int rev = revp[0];

    const int r = tid >> 1;
    const int kh = (tid & 1) << 4;
    const int t = ((mt & 3) << 7) + r;
    const int src_t = rev ? ((T_ - 1 - t + len) & (T_ - 1)) : t;
    const float* arow = x + ((size_t)b * T_ + src_t) * D_;
    const unsigned short* brow = WiT + (size_t)(nt * 128 + r) * D_;

    floatx4 acc[4][4];
#pragma unroll
    for (int i = 0; i < 4; ++i)
#pragma unroll
        for (int j = 0; j < 4; ++j) acc[i][j] = (floatx4){0.f, 0.f, 0.f, 0.f};

    for (int kt = 0; kt < D_ / 32; ++kt) {
        const float4* ap = (const float4*)(arow + kt * 32 + kh);
        float4 a0 = ap[0], a1 = ap[1], a2 = ap[2], a3 = ap[3];
        const uint4* bp = (const uint4*)(brow + kt * 32 + kh);
        uint4 bq0 = bp[0], bq1 = bp[1];
        *(short8*)&a_lds[r][kh]     = pack8(a0, a1);
        *(short8*)&a_lds[r][kh + 8] = pack8(a2, a3);
        *(uint4*)&b_lds[r][kh]     = bq0;
        *(uint4*)&b_lds[r][kh + 8] = bq1;
        __syncthreads();

        short8 af[4], bfr[4];
#pragma unroll
        for (int mi = 0; mi < 4; ++mi)
            af[mi] = *(const short8*)&a_lds[wm * 64 + mi * 16 + (lane & 15)][(lane >> 4) << 3];
#pragma unroll
        for (int ni = 0; ni < 4; ++ni)
            bfr[ni] = *(const short8*)&b_lds[wn * 64 + ni * 16 + (lane & 15)][(lane >> 4) << 3];
#pragma unroll
        for (int mi = 0; mi < 4; ++mi)
#pragma unroll
            for (int ni = 0; ni < 4; ++ni)
                acc[mi][ni] = __builtin_amdgcn_mfma_f32_16x16x32_bf16(af[mi], bfr[ni], acc[mi][ni], 0, 0, 0);
        __syncthreads();
    }

#pragma unroll
    for (int mi = 0; mi < 4; ++mi) {
#pragma unroll
        for (int ni = 0; ni < 4; ++ni) {
            int row = wm * 64 + mi * 16 + ((lane >> 4) << 2);
            int col = nt * 128 + wn * 64 + ni * 16 + (lane & 15);
            float bv = bias[col];
            size_t base = (size_t)(mt * 128 + row) * NG + col;
#pragma unroll
            for (int v = 0; v < 4; ++v)
                zx[base + (size_t)v * NG] = (_Float16)(acc[mi][ni][v] + bv);
        }
    }
}

// ---- persistent LSTM recurrence ----
// 64 blocks = 4 batch-groups(16 batches) x 16 h-blocks(32 units). 4 waves, N-split,
// Wh register-resident. Exchange: packed bf16 h via uncached stores; per-producer
// sentinel dword stored AFTER the end-of-step barrier (whose vmcnt-drain is the ack).
// Consumer thread polls exactly ONE sentinel (its chunk maps to one producer).
__global__ __launch_bounds__(256, 1) void lstm_rec(
    const _Float16* __restrict__ zx, const unsigned short* __restrict__ WhT,
    const float* __restrict__ c0, const float* __restrict__ h0,
    const int* __restrict__ lengths, const int* __restrict__ revp,
    float* __restrict__ out, unsigned short* __restrict__ h_data,
    unsigned int* __restrict__ sent)
{
    __shared__ unsigned short h_lds[16][520];   // 16 batches x 512 units (+pad)

    const int bid = blockIdx.x;
    const int gb = bid & 3, gh = bid >> 2;
    const int tid = threadIdx.x;
    const int lane = tid & 63, w = tid >> 6;
    const int b0 = gb * 16, u0 = gh * 32;
    const int rev = revp[0];

    const int colh = lane & 15;
    const int rr = (lane >> 4) << 2;   // batch base within group (MFMA D rows)
    const int cg = colh >> 3;          // gate-pair selector (0:{i,g} 1:{f,o})
    const int cu = colh & 7;
    const int uu = w * 8 + cu;         // unit within block
    const int khw = (lane >> 4) << 3;  // k-offset within 32-chunk

    int len_v[4]; float c[4];
#pragma unroll
    for (int v = 0; v < 4; ++v) {
        len_v[v] = lengths[b0 + rr + v];
        c[v] = c0[(size_t)(b0 + rr + v) * H_ + u0 + uu];
    }

    // Wh fragments: bw[kk][ni] for gate = ni*2+cg, unit = u0+uu, k = kk*32+khw+0..7
    short8 bw[16][2];
#pragma unroll
    for (int ni = 0; ni < 2; ++ni) {
        const unsigned short* src = WhT + (size_t)((ni * 2 + cg) * H_ + u0 + uu) * D_ + khw;
#pragma unroll
        for (int kk = 0; kk < 16; ++kk)
            bw[kk][ni] = *(const short8*)(src + kk * 32);
    }

    float zxv[2][4];
#pragma unroll
    for (int ni = 0; ni < 2; ++ni)
#pragma unroll
        for (int v = 0; v < 4; ++v)
            zxv[ni][v] = (float)zx[((size_t)(b0 + rr + v) * T_) * NG + (ni * 2 + cg) * H_ + u0 + uu];

    // staging map: thread -> batch row sr2 (=tid&15), producer/chunk ph (=tid>>4)
    // chunk [ph*32, ph*32+32) is produced entirely by block (gb, ph).
    const int sr2 = tid & 15;
    const int ph  = tid >> 4;
    const int scc = ph * 32;

    for (int s = 0; s < T_; ++s) {
        // ---- stage h(s)[16][512] -> LDS ----
        if (s == 0) {
            const float* hp = h0 + (size_t)(b0 + sr2) * H_ + scc;
#pragma unroll
            for (int q = 0; q < 4; ++q) {
                float4 f0 = *(const float4*)(hp + q * 8);
                float4 f1 = *(const float4*)(hp + q * 8 + 4);
                *(short8*)&h_lds[sr2][scc + q * 8] = pack8(f0, f1);
            }
        } else {
            // poll my producer's sentinel (1 uncached dword)
            const unsigned int* sentp = sent + ((size_t)(s & 1) * 4 + gb) * 16 + ph;
            for (;;) {
                unsigned int sv;
                asm volatile("global_load_dword %0, %1, off sc0 sc1\n\t"
                             "s_waitcnt vmcnt(0)"
                             : "=v"(sv) : "v"(sentp) : "memory");
                if (sv == (unsigned int)s) break;
                __builtin_amdgcn_s_sleep(1);
            }
            // load my 32-unit chunk once (64 B packed bf16, uncached)
            const unsigned short* dp = h_data + ((size_t)(s & 1) * B_ + b0 + sr2) * H_ + scc;
            uintx4 q0, q1;
            asm volatile("global_load_dwordx4 %0, %2, off sc0 sc1\n\t"
                         "global_load_dwordx4 %1, %3, off sc0 sc1\n\t"
                         "s_waitcnt vmcnt(0)"
                         : "=&v"(q0), "=&v"(q1)
                         : "v"(dp), "v"(dp + 8) : "memory");
            *(uintx4*)&h_lds[sr2][scc]     = q0;
            *(uintx4*)&h_lds[sr2][scc + 8] = q1;
            asm volatile("global_load_dwordx4 %0, %2, off sc0 sc1\n\t"
                         "global_load_dwordx4 %1, %3, off sc0 sc1\n\t"
                         "s_waitcnt vmcnt(0)"
                         : "=&v"(q0), "=&v"(q1)
                         : "v"(dp + 16), "v"(dp + 24) : "memory");
            *(uintx4*)&h_lds[sr2][scc + 16] = q0;
            *(uintx4*)&h_lds[sr2][scc + 24] = q1;
        }
        __syncthreads();   // (A) h_lds ready

        // ---- z = h @ Wh (full K per wave, 32 MFMA) ----
        floatx4 acc[2];
        acc[0] = (floatx4){0.f, 0.f, 0.f, 0.f};
        acc[1] = (floatx4){0.f, 0.f, 0.f, 0.f};
#pragma unroll
        for (int kk = 0; kk < 16; ++kk) {
            short8 af = *(const short8*)&h_lds[lane & 15][kk * 32 + khw];
            acc[0] = __builtin_amdgcn_mfma_f32_16x16x32_bf16(af, bw[kk][0], acc[0], 0, 0, 0);
            acc[1] = __builtin_amdgcn_mfma_f32_16x16x32_bf16(af, bw[kk][1], acc[1], 0, 0, 0);
        }

        // ---- gates; publish packed h immediately; out stores after ----
        float hn_v[4], cn_v[4];
#pragma unroll
        for (int v = 0; v < 4; ++v) {
            float own0 = acc[0][v] + zxv[0][v];        // gate cg
            float own1 = acc[1][v] + zxv[1][v];        // gate 2+cg
            float oth0 = __shfl_xor(own0, 8);          // gate 1-cg
            float oth1 = __shfl_xor(own1, 8);          // gate 3-cg
            float zi = cg ? oth0 : own0;
            float zf = cg ? own0 : oth0;
            float zg = cg ? oth1 : own1;
            float zo = cg ? own1 : oth1;
            float ig = sigm(zi), fg = sigm(zf);
            float gg = tanh_(zg), og = sigm(zo);
            float cn = fg * c[v] + ig * gg;
            float hn = og * tanh_(cn);
            c[v] = cn; cn_v[v] = cn; hn_v[v] = hn;
            if (cg == 1 && s + 1 < T_) {
                unsigned short* dst =
                    h_data + ((size_t)((s + 1) & 1) * B_ + b0 + rr + v) * H_ + u0 + uu;
                unsigned int val = (unsigned int)f2bf(hn);
                asm volatile("global_store_short %0, %1, off sc0 sc1"
                             :: "v"(dst), "v"(val) : "memory");
            }
        }
#pragma unroll
        for (int v = 0; v < 4; ++v) {
            const int b = b0 + rr + v;
            const int ug = u0 + uu;
            int orig_t = rev ? ((T_ - 1 - s + len_v[v]) & (T_ - 1)) : s;
            if (cg == 0)
                out[((size_t)b * T_ + orig_t) * H_ + ug] = hn_v[v];
            if (s == len_v[v] - 1) {
                size_t fin = (size_t)B_ * T_ * H_;
                if (cg == 0) out[fin + (size_t)b * H_ + ug] = cn_v[v];
                else         out[fin + (size_t)B_ * H_ + (size_t)b * H_ + ug] = hn_v[v];
            }
        }

        __syncthreads();   // (B) vmcnt-drain = publish ack; also protects h_lds reuse

        if (s + 1 < T_) {
            if (tid == 0) {
                unsigned int* sp2 = sent + ((size_t)((s + 1) & 1) * 4 + gb) * 16 + gh;
                unsigned int sval = (unsigned int)(s + 1);
                asm volatile("global_store_dword %0, %1, off sc0 sc1"
                             :: "v"(sp2), "v"(sval) : "memory");
            }
            // zx prefetch for s+1 (cached; hides under next transport wait)
#pragma unroll
            for (int ni = 0; ni < 2; ++ni)
#pragma unroll
                for (int v = 0; v < 4; ++v)
                    zxv[ni][v] = (float)zx[((size_t)(b0 + rr + v) * T_ + s + 1) * NG +
                                           (ni * 2 + cg) * H_ + u0 + uu];
        }
    }
}

extern "C" void kernel_launch(void* const* d_in, const int* in_sizes, int n_in,
                              void* d_out, int out_size, void* d_ws, size_t ws_size,
                              hipStream_t stream)
{
    const float* x       = (const float*)d_in[0];
    const int*   lengths = (const int*)d_in[1];
    const float* c0      = (const float*)d_in[2];
    const float* h0      = (const float*)d_in[3];
    const float* Wi      = (const float*)d_in[4];
    const float* Wh      = (const float*)d_in[5];
    const float* bias    = (const float*)d_in[6];
    const int*   revp    = (const int*)d_in[7];
    float* out = (float*)d_out;

    char* ws = (char*)d_ws;
    const size_t OFF_WIT = 0;
    const size_t OFF_WHT = 2ull << 20;
    const size_t OFF_ZX  = 4ull << 20;
    const size_t OFF_HD  = OFF_ZX + (size_t)B_ * T_ * NG * 2;   // fp16 zx (128 MB)
    const size_t HD_BYTES = 2ull * B_ * H_ * 2;                 // packed bf16 h, dbuf
    const size_t OFF_SENT = OFF_HD + HD_BYTES;
    const size_t SENT_BYTES = 2ull * 4 * 16 * 4;
    const size_t NEED = OFF_SENT + SENT_BYTES;
    if (ws_size < NEED) return;

    unsigned short* WiT = (unsigned short*)(ws + OFF_WIT);
    unsigned short* WhT = (unsigned short*)(ws + OFF_WHT);
    _Float16* zx        = (_Float16*)(ws + OFF_ZX);
    unsigned short* h_data = (unsigned short*)(ws + OFF_HD);
    unsigned int* sent  = (unsigned int*)(ws + OFF_SENT);

    hipMemsetAsync(sent, 0, SENT_BYTES, stream);   // invalidate sentinels each call
    dim3 gt(32, 8, 2);
    transpose_w<<<gt, 256, 0, stream>>>(Wi, Wh, WiT, WhT);
    dim3 g1(256, 16);
    zx_gemm<<<g1, 256, 0, stream>>>(x, lengths, WiT, bias, revp, zx);
    lstm_rec<<<64, 256, 0, stream>>>(zx, WhT, c0, h0, lengths, revp, out, h_data, sent);
}